// Round 4
// baseline (113.633 us; speedup 1.0000x reference)
//
#include <hip/hip_runtime.h>

// Problem constants (from reference): B=4, C=5, H=64, W=64, N=4096
#define Bq  4
#define Cc  5
#define Hh  64
#define Ww  64
#define HW  (Hh * Ww)       // 4096
#define CHW (Cc * HW)       // 20480
#define HW4 (HW / 4)        // 1024 float4 per plane
#define NQMAX 4096          // max bucketable queries
#define Gq  4               // queries per workgroup in grouped attention

__device__ __forceinline__ float fast_exp2(float x) {
#if __has_builtin(__builtin_amdgcn_exp2f)
    return __builtin_amdgcn_exp2f(x);
#else
    return exp2f(x);
#endif
}

// ---------------------------------------------------------------------------
// Kernel A: K/V precompute (float4) + fused y=x copy + FULL query resolution.
// Each wave ballots its 64 queries per batch; the leader lane does ONE
// atomicAdd per (wave,batch) to reserve a contiguous range in qrec[b][...],
// then lanes write the resolved spatial position directly. Order within
// qrec is non-deterministic (atomic order) but the result set per batch is
// deterministic, and every query's output depends only on (b,pos) -> safe.
// ---------------------------------------------------------------------------
__global__ __launch_bounds__(256) void prep_f4(
    const float4* __restrict__ x4,
    const float* __restrict__ kw, const float* __restrict__ kb,
    const float* __restrict__ vw, const float* __restrict__ vb,
    const int* __restrict__ idx_b, const int* __restrict__ idx_h,
    const int* __restrict__ idx_w, int N,
    float4* __restrict__ K4, float4* __restrict__ V4, float4* __restrict__ y4,
    int* __restrict__ qrec,      // [Bq][NQMAX] resolved positions
    int* __restrict__ qcnt)      // [Bq] atomic counters (pre-zeroed)
{
    int t = blockIdx.x * blockDim.x + threadIdx.x;   // 0..4095
    if (t >= NQMAX) return;

    // ---- K/V + y=x copy ----
    {
        int b = t >> 10;            // / HW4
        int p = t & (HW4 - 1);      // % HW4
        const int base = b * (Cc * HW4);
        float4 xi[Cc];
#pragma unroll
        for (int c = 0; c < Cc; ++c) {
            xi[c] = x4[base + c * HW4 + p];
            y4[base + c * HW4 + p] = xi[c];     // fused y = x copy
        }
#pragma unroll
        for (int o = 0; o < Cc; ++o) {
            float kbo = kb[o], vbo = vb[o];
            float4 ka = {kbo, kbo, kbo, kbo};
            float4 va = {vbo, vbo, vbo, vbo};
#pragma unroll
            for (int c = 0; c < Cc; ++c) {
                float kwv = kw[o * Cc + c];
                float vwv = vw[o * Cc + c];
                ka.x += kwv * xi[c].x; ka.y += kwv * xi[c].y;
                ka.z += kwv * xi[c].z; ka.w += kwv * xi[c].w;
                va.x += vwv * xi[c].x; va.y += vwv * xi[c].y;
                va.z += vwv * xi[c].z; va.w += vwv * xi[c].w;
            }
            K4[base + o * HW4 + p] = ka;
            V4[base + o * HW4 + p] = va;
        }
    }

    // ---- resolve queries into per-batch position lists ----
    {
        int lane = threadIdx.x & 63;
        int myb  = (t < N) ? idx_b[t] : -1;
        int pos  = (t < N) ? (idx_h[t] * Ww + idx_w[t]) : 0;
#pragma unroll
        for (int b = 0; b < Bq; ++b) {
            unsigned long long mask = __ballot(myb == b);
            int cnt = (int)__popcll(mask);
            if (cnt) {
                int leader = __ffsll((long long)mask) - 1;   // uniform
                int base = 0;
                if (lane == leader) base = atomicAdd(&qcnt[b], cnt);
                base = __shfl(base, leader, 64);
                if (myb == b) {
                    int rank = (int)__popcll(mask & ((1ull << lane) - 1ull));
                    qrec[b * NQMAX + base + rank] = pos;
                }
            }
        }
    }
}

// ---------------------------------------------------------------------------
// Kernel B: grouped, key-split, TWO-PHASE attention.
// One 256-thread block (4 waves) handles Gq=4 queries of ONE batch; wave w
// owns a disjoint quarter of the 1024 float4 keys (4 iterations).
// Phase 1: stream K only, track per-query max (pure FMA+max, no serial
// softmax chain -> loads pipeline freely). Block-wide max via LDS.
// Phase 2: stream K+V, w=exp2(e-M), plain accumulate (independent FMA
// chains). Butterfly-sum in-wave, LDS combine across waves, scatter.
// ---------------------------------------------------------------------------
__global__ __launch_bounds__(256) void attn_twophase(
    const float* __restrict__ x,
    const float* __restrict__ qw, const float* __restrict__ qb,
    const float4* __restrict__ K4, const float4* __restrict__ V4,
    const float* __restrict__ gamma,
    const int* __restrict__ qrec, const int* __restrict__ qcnt,
    float* __restrict__ y)
{
    __shared__ float sm_max[4][Gq];      // per-wave partial max
    __shared__ float sm_part[4][Gq][6];  // per-wave [l, acc0..4]
    __shared__ int   spos[Gq];           // resolved positions (-1 = invalid)

    const int lane = threadIdx.x & 63;
    const int w    = threadIdx.x >> 6;     // wave 0..3 in block

    // ---- map blockIdx -> (batch b, group g); all-scalar, uniform ----
    int c0 = qcnt[0], c1 = qcnt[1], c2 = qcnt[2], c3 = qcnt[3];
    int cb[4] = {c0, c1, c2, c3};
    int r = blockIdx.x, b = -1, total = 0;
#pragma unroll
    for (int bb = 0; bb < Bq; ++bb) {
        int gb = (cb[bb] + Gq - 1) / Gq;
        if (b < 0) {
            if (r < gb) { b = bb; total = cb[bb]; }
            else        { r -= gb; }
        }
    }
    if (b < 0) return;                     // uniform across whole block
    const int g = r;

    // ---- fetch this block's (up to) Gq resolved positions: ONE load each ----
    int  pos[Gq];
    bool qv[Gq];
#pragma unroll
    for (int j = 0; j < Gq; ++j) {
        int rr = g * Gq + j;
        qv[j]  = (rr < total);             // uniform
        pos[j] = qv[j] ? qrec[b * NQMAX + rr] : -1;
        if (threadIdx.x == 0) spos[j] = pos[j];   // static index j
    }

    // ---- q vectors (log2e folded in); uniform broadcast loads ----
    const float LOG2E = 1.4426950408889634f;
    float q2[Gq][Cc];
#pragma unroll
    for (int j = 0; j < Gq; ++j) {
        if (qv[j]) {
            float xq[Cc];
#pragma unroll
            for (int c = 0; c < Cc; ++c) xq[c] = x[b * CHW + c * HW + pos[j]];
#pragma unroll
            for (int o = 0; o < Cc; ++o) {
                float a = qb[o];
#pragma unroll
                for (int c = 0; c < Cc; ++c) a += qw[o * Cc + c] * xq[c];
                q2[j][o] = a * LOG2E;
            }
        } else {
#pragma unroll
            for (int o = 0; o < Cc; ++o) q2[j][o] = 0.f;
        }
    }

    const float4* Kb = K4 + b * (Cc * HW4);
    const float4* Vb = V4 + b * (Cc * HW4);
    const int p0 = w * (HW4 / 4) + lane;

    // ================= PHASE 1: max only (K stream, no exp) =================
    float m[Gq];
#pragma unroll
    for (int j = 0; j < Gq; ++j) m[j] = -1e30f;

#pragma unroll
    for (int it = 0; it < (HW4 / 4) / 64; ++it) {   // 4 iterations
        int p = p0 + it * 64;
        float4 kc[Cc];
#pragma unroll
        for (int c = 0; c < Cc; ++c) kc[c] = Kb[c * HW4 + p];
#pragma unroll
        for (int j = 0; j < Gq; ++j) {
            float ex = q2[j][0]*kc[0].x + q2[j][1]*kc[1].x + q2[j][2]*kc[2].x
                     + q2[j][3]*kc[3].x + q2[j][4]*kc[4].x;
            float ey = q2[j][0]*kc[0].y + q2[j][1]*kc[1].y + q2[j][2]*kc[2].y
                     + q2[j][3]*kc[3].y + q2[j][4]*kc[4].y;
            float ez = q2[j][0]*kc[0].z + q2[j][1]*kc[1].z + q2[j][2]*kc[2].z
                     + q2[j][3]*kc[3].z + q2[j][4]*kc[4].z;
            float ew = q2[j][0]*kc[0].w + q2[j][1]*kc[1].w + q2[j][2]*kc[2].w
                     + q2[j][3]*kc[3].w + q2[j][4]*kc[4].w;
            m[j] = fmaxf(m[j], fmaxf(fmaxf(ex, ey), fmaxf(ez, ew)));
        }
    }
    // in-wave max butterflies, then cross-wave via LDS
#pragma unroll
    for (int j = 0; j < Gq; ++j) {
#pragma unroll
        for (int off = 32; off >= 1; off >>= 1)
            m[j] = fmaxf(m[j], __shfl_xor(m[j], off, 64));
        if (lane == 0) sm_max[w][j] = m[j];
    }
    __syncthreads();
    float M[Gq];
#pragma unroll
    for (int j = 0; j < Gq; ++j)
        M[j] = fmaxf(fmaxf(sm_max[0][j], sm_max[1][j]),
                     fmaxf(sm_max[2][j], sm_max[3][j]));   // block-uniform

    // ================= PHASE 2: exp-sum (K+V stream, no chain) ==============
    float l[Gq], acc[Gq][Cc];
#pragma unroll
    for (int j = 0; j < Gq; ++j) {
        l[j] = 0.f;
#pragma unroll
        for (int c = 0; c < Cc; ++c) acc[j][c] = 0.f;
    }

#pragma unroll
    for (int it = 0; it < (HW4 / 4) / 64; ++it) {   // 4 iterations
        int p = p0 + it * 64;
        float4 kc[Cc], vc[Cc];
#pragma unroll
        for (int c = 0; c < Cc; ++c) {
            kc[c] = Kb[c * HW4 + p];
            vc[c] = Vb[c * HW4 + p];
        }
#pragma unroll
        for (int j = 0; j < Gq; ++j) {
            float ex = q2[j][0]*kc[0].x + q2[j][1]*kc[1].x + q2[j][2]*kc[2].x
                     + q2[j][3]*kc[3].x + q2[j][4]*kc[4].x;
            float ey = q2[j][0]*kc[0].y + q2[j][1]*kc[1].y + q2[j][2]*kc[2].y
                     + q2[j][3]*kc[3].y + q2[j][4]*kc[4].y;
            float ez = q2[j][0]*kc[0].z + q2[j][1]*kc[1].z + q2[j][2]*kc[2].z
                     + q2[j][3]*kc[3].z + q2[j][4]*kc[4].z;
            float ew = q2[j][0]*kc[0].w + q2[j][1]*kc[1].w + q2[j][2]*kc[2].w
                     + q2[j][3]*kc[3].w + q2[j][4]*kc[4].w;
            float w0 = fast_exp2(ex - M[j]);
            float w1 = fast_exp2(ey - M[j]);
            float w2 = fast_exp2(ez - M[j]);
            float w3 = fast_exp2(ew - M[j]);
            l[j] += (w0 + w1) + (w2 + w3);
#pragma unroll
            for (int c = 0; c < Cc; ++c)
                acc[j][c] += (w0 * vc[c].x + w1 * vc[c].y)
                           + (w2 * vc[c].z + w3 * vc[c].w);
        }
    }

    // in-wave plain-sum butterflies, drop partials to LDS
#pragma unroll
    for (int j = 0; j < Gq; ++j) {
        float ll = l[j];
        float ac[Cc];
#pragma unroll
        for (int c = 0; c < Cc; ++c) ac[c] = acc[j][c];
#pragma unroll
        for (int off = 32; off >= 1; off >>= 1) {
            ll += __shfl_xor(ll, off, 64);
#pragma unroll
            for (int c = 0; c < Cc; ++c) ac[c] += __shfl_xor(ac[c], off, 64);
        }
        if (lane == 0) {
            sm_part[w][j][0] = ll;
#pragma unroll
            for (int c = 0; c < Cc; ++c) sm_part[w][j][1 + c] = ac[c];
        }
    }
    __syncthreads();

    // ---- cross-wave combine + scatter: one thread per (query, channel) ----
    const int tid = threadIdx.x;
    if (tid < Gq * Cc) {
        int j = tid / Cc, c = tid % Cc;
        int pp = spos[j];                  // LDS dynamic index: fine
        if (pp >= 0) {
            float lsum = sm_part[0][j][0] + sm_part[1][j][0]
                       + sm_part[2][j][0] + sm_part[3][j][0];
            float asum = sm_part[0][j][1+c] + sm_part[1][j][1+c]
                       + sm_part[2][j][1+c] + sm_part[3][j][1+c];
            float xi = x[b * CHW + c * HW + pp];
            y[b * CHW + c * HW + pp] = gamma[0] * (asum / lsum) + xi;
        }
    }
}

// ---------------------------------------------------------------------------
// Fallback (no/small workspace or oversized N): scalar inline-KV path.
// ---------------------------------------------------------------------------
__global__ void attn_scatter_inline(
    const float* __restrict__ x,
    const float* __restrict__ qw, const float* __restrict__ qb,
    const float* __restrict__ kw, const float* __restrict__ kb,
    const float* __restrict__ vw, const float* __restrict__ vb,
    const float* __restrict__ gamma,
    const int* __restrict__ idx_b, const int* __restrict__ idx_h,
    const int* __restrict__ idx_w,
    float* __restrict__ y, int N)
{
    int gtid = blockIdx.x * blockDim.x + threadIdx.x;
    int n    = gtid >> 6;
    int lane = threadIdx.x & 63;
    if (n >= N) return;

    const int b   = idx_b[n];
    const int pos = idx_h[n] * Ww + idx_w[n];

    float xq[Cc];
#pragma unroll
    for (int c = 0; c < Cc; ++c) xq[c] = x[b * CHW + c * HW + pos];
    float q[Cc];
#pragma unroll
    for (int o = 0; o < Cc; ++o) {
        float a = qb[o];
#pragma unroll
        for (int c = 0; c < Cc; ++c) a += qw[o * Cc + c] * xq[c];
        q[o] = a;
    }

    const float* Xb = x + b * CHW;
    float m = -1e30f, l = 0.f;
    float acc[Cc] = {0.f, 0.f, 0.f, 0.f, 0.f};

    for (int p = lane; p < HW; p += 64) {
        float xi[Cc];
#pragma unroll
        for (int c = 0; c < Cc; ++c) xi[c] = Xb[c * HW + p];
        float kv_k[Cc], kv_v[Cc];
#pragma unroll
        for (int o = 0; o < Cc; ++o) {
            float ka = kb[o], va = vb[o];
#pragma unroll
            for (int c = 0; c < Cc; ++c) {
                ka += kw[o * Cc + c] * xi[c];
                va += vw[o * Cc + c] * xi[c];
            }
            kv_k[o] = ka;
            kv_v[o] = va;
        }
        float e = q[0]*kv_k[0] + q[1]*kv_k[1] + q[2]*kv_k[2] + q[3]*kv_k[3] + q[4]*kv_k[4];
        float nm  = fmaxf(m, e);
        float a   = __expf(m - nm);
        float wgt = __expf(e - nm);
        l = l * a + wgt;
#pragma unroll
        for (int c = 0; c < Cc; ++c) acc[c] = acc[c] * a + wgt * kv_v[c];
        m = nm;
    }

#pragma unroll
    for (int off = 32; off >= 1; off >>= 1) {
        float m2 = __shfl_xor(m, off, 64);
        float l2 = __shfl_xor(l, off, 64);
        float nm = fmaxf(m, m2);
        float a  = __expf(m - nm);
        float a2 = __expf(m2 - nm);
        l = l * a + l2 * a2;
#pragma unroll
        for (int c = 0; c < Cc; ++c) {
            float o2 = __shfl_xor(acc[c], off, 64);
            acc[c] = acc[c] * a + o2 * a2;
        }
        m = nm;
    }

    if (lane < Cc) {
        int c = lane;
        float xi = x[b * CHW + c * HW + pos];
        y[b * CHW + c * HW + pos] = gamma[0] * (acc[c] / l) + xi;
    }
}

// ---------------------------------------------------------------------------
extern "C" void kernel_launch(void* const* d_in, const int* in_sizes, int n_in,
                              void* d_out, int out_size, void* d_ws, size_t ws_size,
                              hipStream_t stream) {
    const float* x     = (const float*)d_in[0];
    // d_in[1] = x_teature: unused by the reference
    const float* qw    = (const float*)d_in[2];
    const float* qb    = (const float*)d_in[3];
    const float* kw    = (const float*)d_in[4];
    const float* kb    = (const float*)d_in[5];
    const float* vw    = (const float*)d_in[6];
    const float* vb    = (const float*)d_in[7];
    const float* gamma = (const float*)d_in[8];
    const int*   idx_b = (const int*)d_in[9];
    const int*   idx_h = (const int*)d_in[10];
    const int*   idx_w = (const int*)d_in[11];
    const int    N     = in_sizes[9];   // idx_b element count (= index_len)

    float* y = (float*)d_out;

    // workspace layout: K | V | qrec | qcnt
    const size_t kv_floats = (size_t)Bq * CHW;                 // per map
    const size_t need = 2 * kv_floats * sizeof(float)
                      + (size_t)(Bq * NQMAX + Bq) * sizeof(int);

    if (ws_size >= need && N <= NQMAX) {
        float* K = (float*)d_ws;
        float* V = K + kv_floats;
        int* qrec = (int*)(V + kv_floats);
        int* qcnt = qrec + (size_t)Bq * NQMAX;

        hipMemsetAsync(qcnt, 0, Bq * sizeof(int), stream);

        prep_f4<<<(NQMAX + 255) / 256, 256, 0, stream>>>(
            (const float4*)x, kw, kb, vw, vb, idx_b, idx_h, idx_w, N,
            (float4*)K, (float4*)V, (float4*)y, qrec, qcnt);

        // one block per group of Gq queries; +Bq-1 covers per-batch ceil slack
        const int blocks = (N + Gq - 1) / Gq + (Bq - 1);
        attn_twophase<<<blocks, 256, 0, stream>>>(
            x, qw, qb, (const float4*)K, (const float4*)V, gamma,
            qrec, qcnt, y);
    } else {
        hipMemcpyAsync(y, x, (size_t)Bq * CHW * sizeof(float),
                       hipMemcpyDeviceToDevice, stream);
        const int grid_b = (N + 3) / 4;         // 4 waves per 256-thread block
        attn_scatter_inline<<<grid_b, 256, 0, stream>>>(
            x, qw, qb, kw, kb, vw, vb, gamma, idx_b, idx_h, idx_w, y, N);
    }
}